// Round 1
// baseline (83.637 us; speedup 1.0000x reference)
//
#include <hip/hip_runtime.h>

#define IH 128
#define IW 128
#define NCH (8*128)

// Bicubic a=-0.75 half-pixel 2x upsample taps.
// we = kern(-0.25) = [-0.10546875, 0.87890625, 0.26171875, -0.03515625]
// wo = reverse(we)
__global__ __launch_bounds__(256) void pyrup_bicubic_kernel(
        const float* __restrict__ in, float* __restrict__ out) {
    int id = blockIdx.x * blockDim.x + threadIdx.x;
    int ix = id & (IW - 1);
    int iy = (id >> 7) & (IH - 1);
    int nc = id >> 14;   // 0 .. NCH-1

    const float* src = in + (size_t)nc * (IH * IW);
    float* dst = out + (size_t)nc * (size_t)(2 * IH) * (2 * IW);

    const float we0 = -0.10546875f, we1 = 0.87890625f,
                we2 =  0.26171875f, we3 = -0.03515625f;

    // clamped source columns ix-2 .. ix+2
    int c0 = max(ix - 2, 0);
    int c1 = max(ix - 1, 0);
    int c2 = ix;
    int c3 = min(ix + 1, IW - 1);
    int c4 = min(ix + 2, IW - 1);

    float h0[5], h1[5];
#pragma unroll
    for (int k = 0; k < 5; ++k) {
        int r = iy - 2 + k;
        r = min(max(r, 0), IH - 1);
        const float* row = src + r * IW;
        float x0 = row[c0];
        float x1 = row[c1];
        float x2 = row[c2];
        float x3 = row[c3];
        float x4 = row[c4];
        // even output col (ox=2ix): wo taps over cols ix-2..ix+1
        h0[k] = we3 * x0 + we2 * x1 + we1 * x2 + we0 * x3;
        // odd output col (ox=2ix+1): we taps over cols ix-1..ix+2
        h1[k] = we0 * x1 + we1 * x2 + we2 * x3 + we3 * x4;
    }

    // even output row (oy=2iy): wo taps over rows iy-2..iy+1 -> h[0..3]
    float e0 = we3 * h0[0] + we2 * h0[1] + we1 * h0[2] + we0 * h0[3];
    float e1 = we3 * h1[0] + we2 * h1[1] + we1 * h1[2] + we0 * h1[3];
    // odd output row (oy=2iy+1): we taps over rows iy-1..iy+2 -> h[1..4]
    float o0 = we0 * h0[1] + we1 * h0[2] + we2 * h0[3] + we3 * h0[4];
    float o1 = we0 * h1[1] + we1 * h1[2] + we2 * h1[3] + we3 * h1[4];

    size_t orow0 = (size_t)(2 * iy) * (2 * IW) + 2 * ix;
    size_t orow1 = orow0 + (2 * IW);
    *reinterpret_cast<float2*>(dst + orow0) = make_float2(e0, e1);
    *reinterpret_cast<float2*>(dst + orow1) = make_float2(o0, o1);
}

extern "C" void kernel_launch(void* const* d_in, const int* in_sizes, int n_in,
                              void* d_out, int out_size, void* d_ws, size_t ws_size,
                              hipStream_t stream) {
    const float* x = (const float*)d_in[0];
    float* out = (float*)d_out;
    const int total = NCH * IH * IW;          // one thread per input pixel
    const int block = 256;
    const int grid = total / block;           // 65536
    pyrup_bicubic_kernel<<<grid, block, 0, stream>>>(x, out);
}